// Round 3
// baseline (700.564 us; speedup 1.0000x reference)
//
#include <hip/hip_runtime.h>

#define BATCH  200
#define IN_DIM 2312
#define HD1    800
#define HD2    10
#define TWIN   8
#define NSPLIT 16
#define KCH    144   // 15*144=2160; last chunk = 2312-2160 = 152

// ---------------------------------------------------------------------------
// K0a: input [B][C][H][W][T] -> xall [T][B][IN_DIM]
// ---------------------------------------------------------------------------
__global__ __launch_bounds__(512) void k_transpose_in(const float* __restrict__ in,
                                                      float* __restrict__ xall) {
  __shared__ float lds[512];
  int b  = blockIdx.y;
  int i0 = blockIdx.x * 64;
  int tid = threadIdx.x;
  int il = tid >> 3, t = tid & 7;
  int i = i0 + il;
  lds[tid] = (i < IN_DIM) ? in[((size_t)(b * IN_DIM + i) << 3) + t] : 0.f;
  __syncthreads();
  int t2 = tid >> 6, il2 = tid & 63;
  int i2 = i0 + il2;
  if (i2 < IN_DIM)
    xall[((size_t)(t2 * BATCH + b)) * IN_DIM + i2] = lds[il2 * 8 + t2];
}

// ---------------------------------------------------------------------------
// K0c: W1 [800][2312] -> W1T [2312][800]   (once; W1 is timestep-invariant)
// ---------------------------------------------------------------------------
__global__ __launch_bounds__(256) void k_prep_w1t(const float* __restrict__ W1,
                                                  float* __restrict__ W1T) {
  __shared__ float lds[32][33];
  int i0 = blockIdx.x * 32;   // IN_DIM tiles (73)
  int j0 = blockIdx.y * 32;   // HD1 tiles (25)
  int tx = threadIdx.x, ty = threadIdx.y;   // 32 x 8
#pragma unroll
  for (int q = 0; q < 4; q++) {
    int j = j0 + ty + q * 8, i = i0 + tx;
    lds[ty + q * 8][tx] = (j < HD1 && i < IN_DIM) ? W1[(size_t)j * IN_DIM + i] : 0.f;
  }
  __syncthreads();
#pragma unroll
  for (int q = 0; q < 4; q++) {
    int i = i0 + ty + q * 8, j = j0 + tx;
    if (i < IN_DIM)
      W1T[(size_t)i * HD1 + j] = lds[tx][ty + q * 8];
  }
}

// ---------------------------------------------------------------------------
// K0b: init states, copy hebb inputs into output regions
// ---------------------------------------------------------------------------
__global__ __launch_bounds__(256) void k_init(const float* __restrict__ h1in,
                                              const float* __restrict__ h2in,
                                              float* __restrict__ hebb1,
                                              float* __restrict__ hebb2,
                                              float* __restrict__ mem1,
                                              float* __restrict__ spike1,
                                              float* __restrict__ mem2,
                                              float* __restrict__ spike2) {
  int stride = gridDim.x * blockDim.x;
  int n1 = IN_DIM * HD1;
  for (int k = blockIdx.x * blockDim.x + threadIdx.x; k < n1; k += stride) {
    hebb1[k] = h1in[k];
    if (k < HD1 * HD2)  hebb2[k] = h2in[k];
    if (k < BATCH * HD1) { mem1[k] = 0.f; spike1[k] = 0.f; }
    if (k < BATCH * HD2) { mem2[k] = 0.f; spike2[k] = 0.f; }
  }
}

// ---------------------------------------------------------------------------
// K2: split-K GEMM  part[s] = xt[:, kchunk] @ (W1T + alpha1*hebb1)[kchunk, :]
//   M=200 N=800 K=2312. 64x64 tile, 128 thr, 8x4/thread, BK=16, 16 K-chunks.
//   Wc1 combine fused into B staging (W1T precomputed; hebb1 from prev step).
// ---------------------------------------------------------------------------
__global__ __launch_bounds__(128) void k_state_gemm(const float* __restrict__ xt,
                                                    const float* __restrict__ W1T,
                                                    const float* __restrict__ hebb1,
                                                    const float* __restrict__ alpha1,
                                                    float* __restrict__ part) {
  __shared__ __align__(16) float As[16][68];   // [k][m]
  __shared__ __align__(16) float Bs[16][68];   // [k][n]
  int m0 = blockIdx.x * 64;
  int n0 = blockIdx.y * 64;
  int s  = blockIdx.z;
  int kstart = s * KCH;
  int kend   = (s == NSPLIT - 1) ? IN_DIM : kstart + KCH;
  float al = alpha1[0];
  int tid = threadIdx.x;
  int tx = tid & 15, ty = tid >> 4;          // compute map: n=tx*4, m=ty*8
  int a_m = tid >> 2;                        // 0..31 (rows a_m, a_m+32)
  int a_k = (tid & 3) * 4;                   // 0,4,8,12
  int b_k = tid >> 3;                        // 0..15
  int b_n = (tid & 7) * 8;                   // 0,8,..,56 (cols b_n, b_n+4)
  float acc[8][4] = {};
  for (int k0 = kstart; k0 < kend; k0 += 16) {
    // --- stage A (x): 64m x 16k, transposed into [k][m] ---
#pragma unroll
    for (int h = 0; h < 2; h++) {
      int m = m0 + a_m + h * 32;
      float4 av = make_float4(0.f, 0.f, 0.f, 0.f);
      if (m < BATCH && k0 + a_k < kend)
        av = *(const float4*)&xt[(size_t)m * IN_DIM + k0 + a_k];
      As[a_k + 0][a_m + h * 32] = av.x;
      As[a_k + 1][a_m + h * 32] = av.y;
      As[a_k + 2][a_m + h * 32] = av.z;
      As[a_k + 3][a_m + h * 32] = av.w;
    }
    // --- stage B (W1T + al*hebb1): 16k x 64n ---
    {
      int kb = k0 + b_k;
      bool kv = (kb < kend);
      size_t base = (size_t)kb * HD1 + n0 + b_n;
#pragma unroll
      for (int h = 0; h < 2; h++) {
        float4 bv = make_float4(0.f, 0.f, 0.f, 0.f);
        if (kv && n0 + b_n + h * 4 < HD1) {
          float4 w = *(const float4*)&W1T[base + h * 4];
          float4 hb = *(const float4*)&hebb1[base + h * 4];
          bv = make_float4(w.x + al * hb.x, w.y + al * hb.y,
                           w.z + al * hb.z, w.w + al * hb.w);
        }
        *(float4*)&Bs[b_k][b_n + h * 4] = bv;
      }
    }
    __syncthreads();
#pragma unroll
    for (int kk = 0; kk < 16; kk++) {
      float4 a0 = *(const float4*)&As[kk][ty * 8];
      float4 a1 = *(const float4*)&As[kk][ty * 8 + 4];
      float4 b  = *(const float4*)&Bs[kk][tx * 4];
      float am[8] = {a0.x, a0.y, a0.z, a0.w, a1.x, a1.y, a1.z, a1.w};
#pragma unroll
      for (int dm = 0; dm < 8; dm++) {
        acc[dm][0] += am[dm] * b.x;
        acc[dm][1] += am[dm] * b.y;
        acc[dm][2] += am[dm] * b.z;
        acc[dm][3] += am[dm] * b.w;
      }
    }
    __syncthreads();
  }
  int n_base = n0 + tx * 4;
  if (n_base < HD1) {
    float* pp = part + (size_t)s * BATCH * HD1;
#pragma unroll
    for (int dm = 0; dm < 8; dm++) {
      int m = m0 + ty * 8 + dm;
      if (m < BATCH)
        *(float4*)&pp[(size_t)m * HD1 + n_base] =
            make_float4(acc[dm][0], acc[dm][1], acc[dm][2], acc[dm][3]);
    }
  }
}

// ---------------------------------------------------------------------------
// K2b: reduce partials (fixed order -> deterministic) + membrane epilogue
// ---------------------------------------------------------------------------
__global__ __launch_bounds__(256) void k_state_epi(const float* __restrict__ part,
                                                   const float* __restrict__ b1,
                                                   const float* __restrict__ eta1,
                                                   float* __restrict__ mem1,
                                                   float* __restrict__ spike1,
                                                   float* __restrict__ post1) {
  int g = blockIdx.x * blockDim.x + threadIdx.x;
  if (g >= BATCH * (HD1 / 4)) return;
  int m  = g / (HD1 / 4);
  int n4 = (g % (HD1 / 4)) * 4;
  size_t idx = (size_t)m * HD1 + n4;
  float4 sum = *(const float4*)&part[idx];
#pragma unroll
  for (int s = 1; s < NSPLIT; s++) {
    float4 p = *(const float4*)&part[(size_t)s * BATCH * HD1 + idx];
    sum.x += p.x; sum.y += p.y; sum.z += p.z; sum.w += p.w;
  }
  float4 bb = *(const float4*)&b1[n4];
  float4 ee = *(const float4*)&eta1[n4];
  float4 mo = *(const float4*)&mem1[idx];
  float4 so = *(const float4*)&spike1[idx];
  float st[4]  = {sum.x + bb.x, sum.y + bb.y, sum.z + bb.z, sum.w + bb.w};
  float mof[4] = {mo.x, mo.y, mo.z, mo.w};
  float sof[4] = {so.x, so.y, so.z, so.w};
  float eef[4] = {ee.x, ee.y, ee.z, ee.w};
  float mn[4], sp[4], po[4];
#pragma unroll
  for (int q = 0; q < 4; q++) {
    mn[q] = mof[q] * (1.f - sof[q]) * 0.25f + st[q];
    sp[q] = (mn[q] - 0.4f > 0.f) ? 1.f : 0.f;
    po[q] = mn[q] / 0.4f - eef[q];
  }
  *(float4*)&mem1[idx]   = make_float4(mn[0], mn[1], mn[2], mn[3]);
  *(float4*)&spike1[idx] = make_float4(sp[0], sp[1], sp[2], sp[3]);
  *(float4*)&post1[idx]  = make_float4(po[0], po[1], po[2], po[3]);
}

// ---------------------------------------------------------------------------
// K3: hebb1 = clip(0.99*hebb1 - max(beta1[i],0) * (xt^T @ post1)/200, -5, 5)
//   M=2312(i) N=800(j) K=200(b). 64x64 tile, 128 thr, 8x4/thread, BK=16.
// ---------------------------------------------------------------------------
__global__ __launch_bounds__(128) void k_hebb1(const float* __restrict__ xt,
                                               const float* __restrict__ post1,
                                               const float* __restrict__ beta1,
                                               float* __restrict__ hebb1) {
  __shared__ __align__(16) float As[16][68];   // [b][i]
  __shared__ __align__(16) float Bs[16][68];   // [b][j]
  int i0 = blockIdx.x * 64;
  int j0 = blockIdx.y * 64;
  int tid = threadIdx.x;
  int tx = tid & 15, ty = tid >> 4;          // compute: j=tx*4, i=ty*8
  int l_b = tid >> 3;                        // 0..15
  int l_c = (tid & 7) * 8;                   // 0,8,..,56
  float acc[8][4] = {};
  for (int b0 = 0; b0 < BATCH; b0 += 16) {
    int bb = b0 + l_b;
    bool bv_ok = (bb < BATCH);
#pragma unroll
    for (int h = 0; h < 2; h++) {
      float4 av = make_float4(0.f, 0.f, 0.f, 0.f);
      if (bv_ok && i0 + l_c + h * 4 < IN_DIM)
        av = *(const float4*)&xt[(size_t)bb * IN_DIM + i0 + l_c + h * 4];
      *(float4*)&As[l_b][l_c + h * 4] = av;
      float4 pv = make_float4(0.f, 0.f, 0.f, 0.f);
      if (bv_ok && j0 + l_c + h * 4 < HD1)
        pv = *(const float4*)&post1[(size_t)bb * HD1 + j0 + l_c + h * 4];
      *(float4*)&Bs[l_b][l_c + h * 4] = pv;
    }
    __syncthreads();
#pragma unroll
    for (int kk = 0; kk < 16; kk++) {
      float4 a0 = *(const float4*)&As[kk][ty * 8];
      float4 a1 = *(const float4*)&As[kk][ty * 8 + 4];
      float4 b  = *(const float4*)&Bs[kk][tx * 4];
      float am[8] = {a0.x, a0.y, a0.z, a0.w, a1.x, a1.y, a1.z, a1.w};
#pragma unroll
      for (int dm = 0; dm < 8; dm++) {
        acc[dm][0] += am[dm] * b.x;
        acc[dm][1] += am[dm] * b.y;
        acc[dm][2] += am[dm] * b.z;
        acc[dm][3] += am[dm] * b.w;
      }
    }
    __syncthreads();
  }
  int j_base = j0 + tx * 4;
  if (j_base < HD1) {
#pragma unroll
    for (int dm = 0; dm < 8; dm++) {
      int i = i0 + ty * 8 + dm;
      if (i >= IN_DIM) continue;
      float bc = fmaxf(beta1[i], 0.f);
      size_t idx = (size_t)i * HD1 + j_base;
      float4 h = *(const float4*)&hebb1[idx];
      float hv[4] = {h.x, h.y, h.z, h.w};
#pragma unroll
      for (int dn = 0; dn < 4; dn++) {
        float v = 0.99f * hv[dn] - bc * acc[dm][dn] * (1.f / 200.f);
        hv[dn] = fminf(fmaxf(v, -5.f), 5.f);
      }
      *(float4*)&hebb1[idx] = make_float4(hv[0], hv[1], hv[2], hv[3]);
    }
  }
}

// ---------------------------------------------------------------------------
// K4: layer-2 state + membrane update (wave per (b,j), K=800 dot)
// ---------------------------------------------------------------------------
__global__ __launch_bounds__(256) void k_layer2_state(const float* __restrict__ spike1,
                                                      const float* __restrict__ W2,
                                                      const float* __restrict__ b2,
                                                      const float* __restrict__ hebb2,
                                                      const float* __restrict__ alpha2,
                                                      const float* __restrict__ eta2,
                                                      float* __restrict__ mem2,
                                                      float* __restrict__ spike2,
                                                      float* __restrict__ post2,
                                                      float* __restrict__ outs) {
  int wid  = (int)((blockIdx.x * blockDim.x + threadIdx.x) >> 6);
  int lane = threadIdx.x & 63;
  if (wid >= BATCH * HD2) return;
  int b = wid / HD2, j = wid % HD2;
  float al = alpha2[0];
  float acc = 0.f;
  for (int i = lane; i < HD1; i += 64)
    acc += spike1[b * HD1 + i] * (W2[j * HD1 + i] + al * hebb2[i * HD2 + j]);
#pragma unroll
  for (int off = 32; off > 0; off >>= 1) acc += __shfl_down(acc, off, 64);
  if (lane == 0) {
    float state = acc + b2[j];
    int idx = b * HD2 + j;
    float mo = mem2[idx], so = spike2[idx];
    float mn = mo * (1.f - so) * 0.25f + state;
    mem2[idx]   = mn;
    spike2[idx] = (mn - 0.4f > 0.f) ? 1.f : 0.f;
    post2[idx]  = mn / 0.4f - eta2[j];
    outs[idx]   = mn / 0.4f;
  }
}

// ---------------------------------------------------------------------------
// K5: hebb2 update (thread per (i,j), K=200)
// ---------------------------------------------------------------------------
__global__ __launch_bounds__(256) void k_hebb2(const float* __restrict__ spike1,
                                               const float* __restrict__ post2,
                                               const float* __restrict__ beta2,
                                               float* __restrict__ hebb2) {
  int idx = blockIdx.x * blockDim.x + threadIdx.x;
  if (idx >= HD1 * HD2) return;
  int i = idx % HD1, j = idx / HD1;
  float acc = 0.f;
  for (int b = 0; b < BATCH; b++)
    acc += spike1[b * HD1 + i] * post2[b * HD2 + j];
  float bc = fmaxf(beta2[i], 0.f);
  float h = 0.99f * hebb2[i * HD2 + j] - bc * acc * (1.f / 200.f);
  hebb2[i * HD2 + j] = fminf(fmaxf(h, -5.f), 5.f);
}

// ---------------------------------------------------------------------------
extern "C" void kernel_launch(void* const* d_in, const int* in_sizes, int n_in,
                              void* d_out, int out_size, void* d_ws, size_t ws_size,
                              hipStream_t stream) {
  const float* input    = (const float*)d_in[0];
  const float* hebb1_in = (const float*)d_in[1];
  const float* hebb2_in = (const float*)d_in[2];
  const float* W1       = (const float*)d_in[3];
  const float* b1       = (const float*)d_in[4];
  const float* W2       = (const float*)d_in[5];
  const float* b2       = (const float*)d_in[6];
  const float* alpha1   = (const float*)d_in[7];
  const float* alpha2   = (const float*)d_in[8];
  const float* beta1    = (const float*)d_in[9];
  const float* beta2    = (const float*)d_in[10];
  const float* eta1     = (const float*)d_in[11];
  const float* eta2     = (const float*)d_in[12];

  float* out   = (float*)d_out;
  float* outs  = out;
  float* hebb1 = out + BATCH * HD2;
  float* hebb2 = hebb1 + (size_t)IN_DIM * HD1;

  float* ws     = (float*)d_ws;
  float* xall   = ws;                                        // 8*200*2312
  float* W1T    = xall + (size_t)TWIN * BATCH * IN_DIM;      // 2312*800
  float* part   = W1T + (size_t)IN_DIM * HD1;                // 16*200*800
  float* mem1   = part + (size_t)NSPLIT * BATCH * HD1;       // 200*800
  float* spike1 = mem1 + BATCH * HD1;
  float* post1  = spike1 + BATCH * HD1;
  float* mem2   = post1 + BATCH * HD1;                       // 200*10
  float* spike2 = mem2 + BATCH * HD2;
  float* post2  = spike2 + BATCH * HD2;

  k_transpose_in<<<dim3((IN_DIM + 63) / 64, BATCH), 512, 0, stream>>>(input, xall);
  k_prep_w1t<<<dim3(73, 25), dim3(32, 8), 0, stream>>>(W1, W1T);
  k_init<<<1024, 256, 0, stream>>>(hebb1_in, hebb2_in, hebb1, hebb2,
                                   mem1, spike1, mem2, spike2);

  for (int t = 0; t < TWIN; t++) {
    const float* xt = xall + (size_t)t * BATCH * IN_DIM;
    k_state_gemm<<<dim3(4, 13, NSPLIT), 128, 0, stream>>>(xt, W1T, hebb1, alpha1, part);
    k_state_epi<<<dim3((BATCH * (HD1 / 4) + 255) / 256), 256, 0, stream>>>(
        part, b1, eta1, mem1, spike1, post1);
    k_hebb1<<<dim3(37, 13), 256 / 2, 0, stream>>>(xt, post1, beta1, hebb1);
    k_layer2_state<<<dim3((BATCH * HD2 * 64 + 255) / 256), 256, 0, stream>>>(
        spike1, W2, b2, hebb2, alpha2, eta2, mem2, spike2, post2, outs);
    k_hebb2<<<dim3((HD1 * HD2 + 255) / 256), 256, 0, stream>>>(spike1, post2, beta2, hebb2);
  }
}

// Round 4
// 642.404 us; speedup vs baseline: 1.0905x; 1.0905x over previous
//
#include <hip/hip_runtime.h>

#define BATCH  200
#define IN_DIM 2312
#define HD1    800
#define HD2    10
#define TWIN   8

#define MPAD   256    // padded batch rows for GEMM1 A
#define KPAD   2336   // padded in_dim (K of GEMM1, cols of Wc/XA)
#define NPAD   896    // padded hd1 rows for Wc (N of GEMM1)
#define JPAD   832    // padded hd1 rows for postT (M of GEMM2)
#define BPAD   224    // padded batch (K of GEMM2)
#define N2PAD  2432   // padded in_dim rows for XB (N of GEMM2: 19*128)
#define NS1    8      // split-K factor for GEMM1 (73 k-iters of 32)

typedef __attribute__((ext_vector_type(8))) short bf16x8;
typedef __attribute__((ext_vector_type(4))) float f32x4;

// bf16 round-to-nearest-even, bit-level (avoids header type uncertainty)
__device__ __forceinline__ unsigned short f2bf(float x) {
  unsigned u = __builtin_bit_cast(unsigned, x);
  u = (u + 0x7FFFu + ((u >> 16) & 1u)) >> 16;
  return (unsigned short)u;
}
__device__ __forceinline__ float bf2f(unsigned short h) {
  unsigned u = ((unsigned)h) << 16;
  return __builtin_bit_cast(float, u);
}
// exact 3-way split: x = hi + mid + lo + O(2^-24 |x|)
__device__ __forceinline__ void split3(float x, unsigned short& h, unsigned short& m,
                                       unsigned short& l) {
  h = f2bf(x);
  float r1 = x - bf2f(h);
  m = f2bf(r1);
  float r2 = r1 - bf2f(m);
  l = f2bf(r2);
}

// ---------------------------------------------------------------------------
// zero the contiguous ushort split-array span (pads must be 0 for guard-free GEMMs)
// span = 1,283,328 uint4 exactly (5013 blocks x 256)
// ---------------------------------------------------------------------------
__global__ __launch_bounds__(256) void k_zero(uint4* __restrict__ p) {
  p[blockIdx.x * 256 + threadIdx.x] = make_uint4(0, 0, 0, 0);
}

// ---------------------------------------------------------------------------
// generic 32x32 tiled transpose: src [R][C] -> dst [C][R]
// ---------------------------------------------------------------------------
__global__ __launch_bounds__(256) void k_transpose(const float* __restrict__ src,
                                                   float* __restrict__ dst, int R, int C) {
  __shared__ float t[32][33];
  int r0 = blockIdx.x * 32, c0 = blockIdx.y * 32;
  int tx = threadIdx.x, ty = threadIdx.y;   // 32 x 8
#pragma unroll
  for (int q = 0; q < 4; q++) {
    int r = r0 + ty + q * 8, c = c0 + tx;
    if (r < R && c < C) t[ty + q * 8][tx] = src[(size_t)r * C + c];
  }
  __syncthreads();
#pragma unroll
  for (int q = 0; q < 4; q++) {
    int c = c0 + ty + q * 8, r = r0 + tx;
    if (c < C && r < R) dst[(size_t)c * R + r] = t[tx][ty + q * 8];
  }
}

// ---------------------------------------------------------------------------
// init: hebb2 copy to out, zero membrane/spike states
// ---------------------------------------------------------------------------
__global__ __launch_bounds__(256) void k_init(const float* __restrict__ h2in,
                                              float* __restrict__ hebb2,
                                              float* __restrict__ mem1,
                                              float* __restrict__ spike1,
                                              float* __restrict__ mem2,
                                              float* __restrict__ spike2) {
  int k = blockIdx.x * blockDim.x + threadIdx.x;
  if (k < BATCH * HD1) { mem1[k] = 0.f; spike1[k] = 0.f; }
  if (k < HD1 * HD2) hebb2[k] = h2in[k];
  if (k < BATCH * HD2) { mem2[k] = 0.f; spike2[k] = 0.f; }
}

// ---------------------------------------------------------------------------
// initial Wc split: Wc[j][i] = W1[j][i] + alpha1 * H[j][i]  (t=0 only;
// subsequent steps produce Wc in k_gemm2's epilogue)
// ---------------------------------------------------------------------------
__global__ __launch_bounds__(256) void k_split_wc(const float* __restrict__ W1,
                                                  const float* __restrict__ H,
                                                  const float* __restrict__ alpha1,
                                                  unsigned short* __restrict__ Wch,
                                                  unsigned short* __restrict__ Wcm,
                                                  unsigned short* __restrict__ Wcl) {
  int id = blockIdx.x * blockDim.x + threadIdx.x;
  if (id >= HD1 * (IN_DIM / 8)) return;
  int j = id / (IN_DIM / 8);
  int i8 = (id % (IN_DIM / 8)) * 8;
  float al = alpha1[0];
  size_t sx = (size_t)j * IN_DIM + i8;
  size_t dx = (size_t)j * KPAD + i8;
  unsigned short h[8], m[8], l[8];
#pragma unroll
  for (int q = 0; q < 8; q++) split3(W1[sx + q] + al * H[sx + q], h[q], m[q], l[q]);
#pragma unroll
  for (int q = 0; q < 8; q++) { Wch[dx + q] = h[q]; Wcm[dx + q] = m[q]; Wcl[dx + q] = l[q]; }
}

// ---------------------------------------------------------------------------
// per-step x split: input [B][IN_DIM][T] slice t -> XA (h/m/l) [MPAD][KPAD]
// and XB (h/m/l) [N2PAD][BPAD]  (32x32 tiles, transpose via LDS)
// ---------------------------------------------------------------------------
__global__ __launch_bounds__(256) void k_split_x(const float* __restrict__ in, int t,
                                                 unsigned short* __restrict__ XAh,
                                                 unsigned short* __restrict__ XAm,
                                                 unsigned short* __restrict__ XAl,
                                                 unsigned short* __restrict__ XBh,
                                                 unsigned short* __restrict__ XBm,
                                                 unsigned short* __restrict__ XBl) {
  __shared__ unsigned short sh[3][32][33];
  int i0 = blockIdx.x * 32, b0 = blockIdx.y * 32;
  int il = threadIdx.x & 31, q0 = threadIdx.x >> 5;
#pragma unroll
  for (int q = 0; q < 4; q++) {
    int bl = q0 + q * 8;
    int b = b0 + bl, i = i0 + il;
    float v = (b < BATCH && i < IN_DIM) ? in[(((size_t)b * IN_DIM + i) << 3) + t] : 0.f;
    unsigned short vh, vm, vl;
    split3(v, vh, vm, vl);
    size_t ax = (size_t)(b0 + bl) * KPAD + i;
    XAh[ax] = vh; XAm[ax] = vm; XAl[ax] = vl;
    sh[0][bl][il] = vh; sh[1][bl][il] = vm; sh[2][bl][il] = vl;
  }
  __syncthreads();
#pragma unroll
  for (int q = 0; q < 4; q++) {
    int il2 = q0 + q * 8;   // i-local row
    int bl2 = il;           // b-local col
    size_t bx = (size_t)(i0 + il2) * BPAD + b0 + bl2;
    XBh[bx] = sh[0][bl2][il2]; XBm[bx] = sh[1][bl2][il2]; XBl[bx] = sh[2][bl2][il2];
  }
}

// ---------------------------------------------------------------------------
// GEMM1 (MFMA, split-K): part[s] = x @ Wc^T-ish  (M=200pad256, N=800pad896, K=2312pad2336)
// A = XA [m][k] (K-contig), B = Wc [n][k] (K-contig). 6 split passes into fp32 acc.
// block tile 64(M)x128(N), 4 waves (2x2), wave tile 32x64 = 2x4 16x16 frags.
// ---------------------------------------------------------------------------
__global__ __launch_bounds__(256) void k_gemm1(
    const unsigned short* __restrict__ XAh, const unsigned short* __restrict__ XAm,
    const unsigned short* __restrict__ XAl, const unsigned short* __restrict__ Wch,
    const unsigned short* __restrict__ Wcm, const unsigned short* __restrict__ Wcl,
    float* __restrict__ part) {
  __shared__ __align__(16) unsigned short Ab[3][64 * 40];    // row stride 80B
  __shared__ __align__(16) unsigned short Bb[3][128 * 40];
  int m0 = blockIdx.x * 64, n0 = blockIdx.y * 128, s = blockIdx.z;
  int it0 = s * 9, it1 = (s == NS1 - 1) ? 73 : s * 9 + 9;
  int tid = threadIdx.x;
  int r = tid >> 2, g = tid & 3;
  int w = tid >> 6, lane = tid & 63;
  int wm = w >> 1, wn = w & 1, lr = lane & 15, lg = lane >> 4;
  f32x4 acc[2][4] = {};
  for (int it = it0; it < it1; ++it) {
    int k0 = it * 32;
    size_t ga = (size_t)(m0 + r) * KPAD + k0 + g * 8;
    uint4 a0 = *(const uint4*)&XAh[ga];
    uint4 a1 = *(const uint4*)&XAm[ga];
    uint4 a2 = *(const uint4*)&XAl[ga];
    size_t gb0 = (size_t)(n0 + r) * KPAD + k0 + g * 8;
    size_t gb1 = (size_t)(n0 + r + 64) * KPAD + k0 + g * 8;
    uint4 b0 = *(const uint4*)&Wch[gb0];
    uint4 b1 = *(const uint4*)&Wcm[gb0];
    uint4 b2 = *(const uint4*)&Wcl[gb0];
    uint4 b3 = *(const uint4*)&Wch[gb1];
    uint4 b4 = *(const uint4*)&Wcm[gb1];
    uint4 b5 = *(const uint4*)&Wcl[gb1];
    __syncthreads();
    int la = r * 40 + g * 8;
    *(uint4*)&Ab[0][la] = a0; *(uint4*)&Ab[1][la] = a1; *(uint4*)&Ab[2][la] = a2;
    *(uint4*)&Bb[0][la] = b0; *(uint4*)&Bb[1][la] = b1; *(uint4*)&Bb[2][la] = b2;
    int lb = (r + 64) * 40 + g * 8;
    *(uint4*)&Bb[0][lb] = b3; *(uint4*)&Bb[1][lb] = b4; *(uint4*)&Bb[2][lb] = b5;
    __syncthreads();
    bf16x8 ah[2], am[2], al[2];
#pragma unroll
    for (int fm = 0; fm < 2; fm++) {
      int row = (wm * 32 + fm * 16 + lr) * 40 + lg * 8;
      ah[fm] = *(const bf16x8*)&Ab[0][row];
      am[fm] = *(const bf16x8*)&Ab[1][row];
      al[fm] = *(const bf16x8*)&Ab[2][row];
    }
#pragma unroll
    for (int fn = 0; fn < 4; fn++) {
      int rown = (wn * 64 + fn * 16 + lr) * 40 + lg * 8;
      bf16x8 bh = *(const bf16x8*)&Bb[0][rown];
      bf16x8 bm = *(const bf16x8*)&Bb[1][rown];
      bf16x8 bl = *(const bf16x8*)&Bb[2][rown];
#pragma unroll
      for (int fm = 0; fm < 2; fm++) {
        f32x4 c = acc[fm][fn];
        c = __builtin_amdgcn_mfma_f32_16x16x32_bf16(ah[fm], bh, c, 0, 0, 0);
        c = __builtin_amdgcn_mfma_f32_16x16x32_bf16(ah[fm], bm, c, 0, 0, 0);
        c = __builtin_amdgcn_mfma_f32_16x16x32_bf16(am[fm], bh, c, 0, 0, 0);
        c = __builtin_amdgcn_mfma_f32_16x16x32_bf16(ah[fm], bl, c, 0, 0, 0);
        c = __builtin_amdgcn_mfma_f32_16x16x32_bf16(al[fm], bh, c, 0, 0, 0);
        c = __builtin_amdgcn_mfma_f32_16x16x32_bf16(am[fm], bm, c, 0, 0, 0);
        acc[fm][fn] = c;
      }
    }
  }
  float* pp = part + (size_t)s * BATCH * HD1;
#pragma unroll
  for (int fm = 0; fm < 2; fm++)
#pragma unroll
    for (int fn = 0; fn < 4; fn++) {
      int n = n0 + wn * 64 + fn * 16 + lr;
      if (n >= HD1) continue;
      int mb = m0 + wm * 32 + fm * 16 + lg * 4;
#pragma unroll
      for (int r4 = 0; r4 < 4; r4++) {
        int m = mb + r4;
        if (m < BATCH) pp[(size_t)m * HD1 + n] = acc[fm][fn][r4];
      }
    }
}

// ---------------------------------------------------------------------------
// epilogue: fixed-order split-K reduce + membrane update; writes mem1, spike1,
// and postT (h/m/l bf16 splits, transposed [j][b]) for GEMM2's A operand.
// ---------------------------------------------------------------------------
__global__ __launch_bounds__(256) void k_state_epi(const float* __restrict__ part,
                                                   const float* __restrict__ b1,
                                                   const float* __restrict__ eta1,
                                                   float* __restrict__ mem1,
                                                   float* __restrict__ spike1,
                                                   unsigned short* __restrict__ PTh,
                                                   unsigned short* __restrict__ PTm,
                                                   unsigned short* __restrict__ PTl) {
  int gidx = blockIdx.x * blockDim.x + threadIdx.x;
  if (gidx >= BATCH * (HD1 / 4)) return;
  int m = gidx / (HD1 / 4);
  int n4 = (gidx % (HD1 / 4)) * 4;
  size_t idx = (size_t)m * HD1 + n4;
  float4 sum = *(const float4*)&part[idx];
#pragma unroll
  for (int s = 1; s < NS1; s++) {
    float4 p = *(const float4*)&part[(size_t)s * BATCH * HD1 + idx];
    sum.x += p.x; sum.y += p.y; sum.z += p.z; sum.w += p.w;
  }
  float4 bb = *(const float4*)&b1[n4];
  float4 ee = *(const float4*)&eta1[n4];
  float4 mo = *(const float4*)&mem1[idx];
  float4 so = *(const float4*)&spike1[idx];
  float st[4]  = {sum.x + bb.x, sum.y + bb.y, sum.z + bb.z, sum.w + bb.w};
  float mof[4] = {mo.x, mo.y, mo.z, mo.w};
  float sof[4] = {so.x, so.y, so.z, so.w};
  float eef[4] = {ee.x, ee.y, ee.z, ee.w};
  float mn[4], sp[4];
#pragma unroll
  for (int q = 0; q < 4; q++) {
    mn[q] = mof[q] * (1.f - sof[q]) * 0.25f + st[q];
    sp[q] = (mn[q] - 0.4f > 0.f) ? 1.f : 0.f;
    float po = mn[q] * 2.5f - eef[q];
    unsigned short vh, vm, vl;
    split3(po, vh, vm, vl);
    size_t px = (size_t)(n4 + q) * BPAD + m;
    PTh[px] = vh; PTm[px] = vm; PTl[px] = vl;
  }
  *(float4*)&mem1[idx]   = make_float4(mn[0], mn[1], mn[2], mn[3]);
  *(float4*)&spike1[idx] = make_float4(sp[0], sp[1], sp[2], sp[3]);
}

// ---------------------------------------------------------------------------
// GEMM2 (MFMA): G[j][i] = sum_b post[b][j] x[b][i]  (M=800pad832, N=2312pad2432,
// K=200pad224). A = postT [j][b], B = XB [i][b]. Fused epilogue: H (transposed
// hebb1) update + next-step Wc bf16 splits (Wc[j][i] = W1[j][i] + a1*H[j][i]).
// ---------------------------------------------------------------------------
__global__ __launch_bounds__(256) void k_gemm2(
    const unsigned short* __restrict__ PTh, const unsigned short* __restrict__ PTm,
    const unsigned short* __restrict__ PTl, const unsigned short* __restrict__ XBh,
    const unsigned short* __restrict__ XBm, const unsigned short* __restrict__ XBl,
    const float* __restrict__ beta1, const float* __restrict__ W1,
    const float* __restrict__ alpha1, float* __restrict__ H,
    unsigned short* __restrict__ Wch, unsigned short* __restrict__ Wcm,
    unsigned short* __restrict__ Wcl) {
  __shared__ __align__(16) unsigned short Ab[3][64 * 40];
  __shared__ __align__(16) unsigned short Bb[3][128 * 40];
  int m0 = blockIdx.x * 64, n0 = blockIdx.y * 128;
  int tid = threadIdx.x;
  int r = tid >> 2, g = tid & 3;
  int w = tid >> 6, lane = tid & 63;
  int wm = w >> 1, wn = w & 1, lr = lane & 15, lg = lane >> 4;
  f32x4 acc[2][4] = {};
  for (int it = 0; it < 7; ++it) {
    int k0 = it * 32;
    size_t ga = (size_t)(m0 + r) * BPAD + k0 + g * 8;
    uint4 a0 = *(const uint4*)&PTh[ga];
    uint4 a1 = *(const uint4*)&PTm[ga];
    uint4 a2 = *(const uint4*)&PTl[ga];
    size_t gb0 = (size_t)(n0 + r) * BPAD + k0 + g * 8;
    size_t gb1 = (size_t)(n0 + r + 64) * BPAD + k0 + g * 8;
    uint4 b0 = *(const uint4*)&XBh[gb0];
    uint4 b1 = *(const uint4*)&XBm[gb0];
    uint4 b2 = *(const uint4*)&XBl[gb0];
    uint4 b3 = *(const uint4*)&XBh[gb1];
    uint4 b4 = *(const uint4*)&XBm[gb1];
    uint4 b5 = *(const uint4*)&XBl[gb1];
    __syncthreads();
    int la = r * 40 + g * 8;
    *(uint4*)&Ab[0][la] = a0; *(uint4*)&Ab[1][la] = a1; *(uint4*)&Ab[2][la] = a2;
    *(uint4*)&Bb[0][la] = b0; *(uint4*)&Bb[1][la] = b1; *(uint4*)&Bb[2][la] = b2;
    int lb = (r + 64) * 40 + g * 8;
    *(uint4*)&Bb[0][lb] = b3; *(uint4*)&Bb[1][lb] = b4; *(uint4*)&Bb[2][lb] = b5;
    __syncthreads();
    bf16x8 ah[2], am[2], al[2];
#pragma unroll
    for (int fm = 0; fm < 2; fm++) {
      int row = (wm * 32 + fm * 16 + lr) * 40 + lg * 8;
      ah[fm] = *(const bf16x8*)&Ab[0][row];
      am[fm] = *(const bf16x8*)&Ab[1][row];
      al[fm] = *(const bf16x8*)&Ab[2][row];
    }
#pragma unroll
    for (int fn = 0; fn < 4; fn++) {
      int rown = (wn * 64 + fn * 16 + lr) * 40 + lg * 8;
      bf16x8 bh = *(const bf16x8*)&Bb[0][rown];
      bf16x8 bm = *(const bf16x8*)&Bb[1][rown];
      bf16x8 bl = *(const bf16x8*)&Bb[2][rown];
#pragma unroll
      for (int fm = 0; fm < 2; fm++) {
        f32x4 c = acc[fm][fn];
        c = __builtin_amdgcn_mfma_f32_16x16x32_bf16(ah[fm], bh, c, 0, 0, 0);
        c = __builtin_amdgcn_mfma_f32_16x16x32_bf16(ah[fm], bm, c, 0, 0, 0);
        c = __builtin_amdgcn_mfma_f32_16x16x32_bf16(am[fm], bh, c, 0, 0, 0);
        c = __builtin_amdgcn_mfma_f32_16x16x32_bf16(ah[fm], bl, c, 0, 0, 0);
        c = __builtin_amdgcn_mfma_f32_16x16x32_bf16(al[fm], bh, c, 0, 0, 0);
        c = __builtin_amdgcn_mfma_f32_16x16x32_bf16(am[fm], bm, c, 0, 0, 0);
        acc[fm][fn] = c;
      }
    }
  }
  float al1 = alpha1[0];
#pragma unroll
  for (int fm = 0; fm < 2; fm++)
#pragma unroll
    for (int fn = 0; fn < 4; fn++) {
      int i = n0 + wn * 64 + fn * 16 + lr;
      if (i >= IN_DIM) continue;
      float bc = fmaxf(beta1[i], 0.f);
      int jb = m0 + wm * 32 + fm * 16 + lg * 4;
#pragma unroll
      for (int r4 = 0; r4 < 4; r4++) {
        int j = jb + r4;
        if (j >= HD1) continue;
        size_t hx = (size_t)j * IN_DIM + i;
        float h = 0.99f * H[hx] - bc * acc[fm][fn][r4] * (1.f / 200.f);
        h = fminf(fmaxf(h, -5.f), 5.f);
        H[hx] = h;
        unsigned short vh, vm, vl;
        split3(W1[hx] + al1 * h, vh, vm, vl);
        size_t wx = (size_t)j * KPAD + i;
        Wch[wx] = vh; Wcm[wx] = vm; Wcl[wx] = vl;
      }
    }
}

// ---------------------------------------------------------------------------
// layer-2 state + membrane (wave per (b,j), K=800) — unchanged
// ---------------------------------------------------------------------------
__global__ __launch_bounds__(256) void k_layer2_state(const float* __restrict__ spike1,
                                                      const float* __restrict__ W2,
                                                      const float* __restrict__ b2,
                                                      const float* __restrict__ hebb2,
                                                      const float* __restrict__ alpha2,
                                                      const float* __restrict__ eta2,
                                                      float* __restrict__ mem2,
                                                      float* __restrict__ spike2,
                                                      float* __restrict__ post2,
                                                      float* __restrict__ outs) {
  int wid  = (int)((blockIdx.x * blockDim.x + threadIdx.x) >> 6);
  int lane = threadIdx.x & 63;
  if (wid >= BATCH * HD2) return;
  int b = wid / HD2, j = wid % HD2;
  float al = alpha2[0];
  float acc = 0.f;
  for (int i = lane; i < HD1; i += 64)
    acc += spike1[b * HD1 + i] * (W2[j * HD1 + i] + al * hebb2[i * HD2 + j]);
#pragma unroll
  for (int off = 32; off > 0; off >>= 1) acc += __shfl_down(acc, off, 64);
  if (lane == 0) {
    float state = acc + b2[j];
    int idx = b * HD2 + j;
    float mo = mem2[idx], so = spike2[idx];
    float mn = mo * (1.f - so) * 0.25f + state;
    mem2[idx]   = mn;
    spike2[idx] = (mn - 0.4f > 0.f) ? 1.f : 0.f;
    post2[idx]  = mn * 2.5f - eta2[j];
    outs[idx]   = mn * 2.5f;
  }
}

// ---------------------------------------------------------------------------
// hebb2 update (thread per (i,j), K=200) — unchanged
// ---------------------------------------------------------------------------
__global__ __launch_bounds__(256) void k_hebb2(const float* __restrict__ spike1,
                                               const float* __restrict__ post2,
                                               const float* __restrict__ beta2,
                                               float* __restrict__ hebb2) {
  int idx = blockIdx.x * blockDim.x + threadIdx.x;
  if (idx >= HD1 * HD2) return;
  int i = idx % HD1, j = idx / HD1;
  float acc = 0.f;
  for (int b = 0; b < BATCH; b++)
    acc += spike1[b * HD1 + i] * post2[b * HD2 + j];
  float bc = fmaxf(beta2[i], 0.f);
  float h = 0.99f * hebb2[i * HD2 + j] - bc * acc * (1.f / 200.f);
  hebb2[i * HD2 + j] = fminf(fmaxf(h, -5.f), 5.f);
}

// ---------------------------------------------------------------------------
extern "C" void kernel_launch(void* const* d_in, const int* in_sizes, int n_in,
                              void* d_out, int out_size, void* d_ws, size_t ws_size,
                              hipStream_t stream) {
  const float* input    = (const float*)d_in[0];
  const float* hebb1_in = (const float*)d_in[1];
  const float* hebb2_in = (const float*)d_in[2];
  const float* W1       = (const float*)d_in[3];
  const float* b1       = (const float*)d_in[4];
  const float* W2       = (const float*)d_in[5];
  const float* b2       = (const float*)d_in[6];
  const float* alpha1   = (const float*)d_in[7];
  const float* alpha2   = (const float*)d_in[8];
  const float* beta1    = (const float*)d_in[9];
  const float* beta2    = (const float*)d_in[10];
  const float* eta1     = (const float*)d_in[11];
  const float* eta2     = (const float*)d_in[12];

  float* out      = (float*)d_out;
  float* outs     = out;                               // [200][10]
  float* hebb1out = out + BATCH * HD2;                 // [2312][800]
  float* hebb2o   = hebb1out + (size_t)IN_DIM * HD1;   // [800][10]

  // --- ws layout: ushort split arrays first (contiguous, zeroed once/call) ---
  unsigned short* us = (unsigned short*)d_ws;
  unsigned short* XAh = us;                    // 256*2336
  unsigned short* XAm = XAh + (size_t)MPAD * KPAD;
  unsigned short* XAl = XAm + (size_t)MPAD * KPAD;
  unsigned short* XBh = XAl + (size_t)MPAD * KPAD;     // 2432*224
  unsigned short* XBm = XBh + (size_t)N2PAD * BPAD;
  unsigned short* XBl = XBm + (size_t)N2PAD * BPAD;
  unsigned short* Wch = XBl + (size_t)N2PAD * BPAD;    // 896*2336
  unsigned short* Wcm = Wch + (size_t)NPAD * KPAD;
  unsigned short* Wcl = Wcm + (size_t)NPAD * KPAD;
  unsigned short* PTh = Wcl + (size_t)NPAD * KPAD;     // 832*224
  unsigned short* PTm = PTh + (size_t)JPAD * BPAD;
  unsigned short* PTl = PTm + (size_t)JPAD * BPAD;
  size_t us_total = 3 * ((size_t)MPAD * KPAD + (size_t)N2PAD * BPAD +
                         (size_t)NPAD * KPAD + (size_t)JPAD * BPAD);  // = 10,266,624
  float* fp = (float*)(us + us_total);
  float* part   = fp;                                  // 8*200*800
  float* H      = part + (size_t)NS1 * BATCH * HD1;    // 800*2312 (hebb1 transposed)
  float* mem1   = H + (size_t)HD1 * IN_DIM;            // 200*800
  float* spike1 = mem1 + BATCH * HD1;
  float* mem2   = spike1 + BATCH * HD1;                // 200*10
  float* spike2 = mem2 + BATCH * HD2;
  float* post2  = spike2 + BATCH * HD2;

  // init: zero split-array pads, transpose hebb1_in -> H, states, initial Wc
  k_zero<<<5013, 256, 0, stream>>>((uint4*)us);
  k_transpose<<<dim3(73, 25), dim3(32, 8), 0, stream>>>(hebb1_in, H, IN_DIM, HD1);
  k_init<<<625, 256, 0, stream>>>(hebb2_in, hebb2o, mem1, spike1, mem2, spike2);
  k_split_wc<<<(HD1 * (IN_DIM / 8) + 255) / 256, 256, 0, stream>>>(W1, H, alpha1,
                                                                   Wch, Wcm, Wcl);

  for (int t = 0; t < TWIN; t++) {
    k_split_x<<<dim3(73, 7), 256, 0, stream>>>(input, t, XAh, XAm, XAl, XBh, XBm, XBl);
    k_gemm1<<<dim3(4, 7, NS1), 256, 0, stream>>>(XAh, XAm, XAl, Wch, Wcm, Wcl, part);
    k_state_epi<<<(BATCH * (HD1 / 4) + 255) / 256, 256, 0, stream>>>(
        part, b1, eta1, mem1, spike1, PTh, PTm, PTl);
    k_layer2_state<<<(BATCH * HD2 * 64 + 255) / 256, 256, 0, stream>>>(
        spike1, W2, b2, hebb2o, alpha2, eta2, mem2, spike2, post2, outs);
    k_hebb2<<<(HD1 * HD2 + 255) / 256, 256, 0, stream>>>(spike1, post2, beta2, hebb2o);
    k_gemm2<<<dim3(13, 19), 256, 0, stream>>>(PTh, PTm, PTl, XBh, XBm, XBl,
                                              beta1, W1, alpha1, H, Wch, Wcm, Wcl);
  }
  k_transpose<<<dim3(25, 73), dim3(32, 8), 0, stream>>>(H, hebb1out, HD1, IN_DIM);
}